// Round 8
// baseline (247.252 us; speedup 1.0000x reference)
//
#include <hip/hip_runtime.h>

#define LSEQ 4096
#define DMODEL 1024
#define HTOT 16
#define NAR 8
#define DHEAD 64
#define QKVS 3072  // fused QKV row stride

typedef unsigned short u16;
typedef unsigned int u32;
typedef __attribute__((ext_vector_type(8))) short bf16x8;
typedef __attribute__((ext_vector_type(4))) short bf16x4;
typedef __attribute__((ext_vector_type(4))) float f32x4;
typedef __attribute__((ext_vector_type(4))) unsigned int u32x4;

typedef __attribute__((address_space(1))) void gvoid;
typedef __attribute__((address_space(3))) void lvoid;

__device__ __forceinline__ void cp16(const void* g, void* l) {
    // async global->LDS, 16B per lane; LDS dest = wave-uniform base + lane*16
    __builtin_amdgcn_global_load_lds((gvoid*)(void*)g, (lvoid*)l, 16, 0, 0);
}

// round-to-nearest-even fp32 -> bf16
__device__ __forceinline__ u16 f2bf(float f) {
    u32 x = __float_as_uint(f);
    return (u16)((x + 0x7fffu + ((x >> 16) & 1u)) >> 16);
}
// truncation-pack two fp32 -> packed bf16x2 (1 v_perm_b32)
__device__ __forceinline__ u32 packtr(float lo, float hi) {
    return __builtin_amdgcn_perm(__float_as_uint(hi), __float_as_uint(lo), 0x07060302u);
}

// ---------------------------------------------------------------------------
// X (fp32) -> Xb (bf16, truncated) once.
// ---------------------------------------------------------------------------
__global__ __launch_bounds__(256) void xcast(const float* __restrict__ X, u16* __restrict__ Xb)
{
    const size_t i = (size_t)(blockIdx.x * 256 + threadIdx.x) * 8;
    float4 a0 = *(const float4*)(X + i);
    float4 a1 = *(const float4*)(X + i + 4);
    uint4 pk;
    pk.x = packtr(a0.x, a0.y); pk.y = packtr(a0.z, a0.w);
    pk.z = packtr(a1.x, a1.y); pk.w = packtr(a1.z, a1.w);
    *(uint4*)(Xb + i) = pk;
}

// ---------------------------------------------------------------------------
// Fused transpose of Wq/Wk/Wv: 1024x1024 fp32 -> bf16 (D = S^T), z selects.
// ---------------------------------------------------------------------------
__global__ __launch_bounds__(256) void transp_cvt3(
    const float* __restrict__ Wq, const float* __restrict__ Wk,
    const float* __restrict__ Wv, u16* __restrict__ D)
{
    __shared__ u16 T[64][72];
    const float* S = (blockIdx.z == 0) ? Wq : ((blockIdx.z == 1) ? Wk : Wv);
    u16* Dz = D + (size_t)blockIdx.z * 1024 * 1024;
    const int tid = threadIdx.x;
    const int bx = blockIdx.x, by = blockIdx.y;
#pragma unroll
    for (int i = 0; i < 4; ++i) {
        int id = tid + i * 256;
        int fr = id >> 4, fc = id & 15;
        float4 v = *(const float4*)(S + (size_t)(by * 64 + fr) * 1024 + bx * 64 + fc * 4);
        T[fc * 4 + 0][fr] = f2bf(v.x);
        T[fc * 4 + 1][fr] = f2bf(v.y);
        T[fc * 4 + 2][fr] = f2bf(v.z);
        T[fc * 4 + 3][fr] = f2bf(v.w);
    }
    __syncthreads();
#pragma unroll
    for (int i = 0; i < 2; ++i) {
        int id = tid + i * 256;
        int c = id >> 3, g = id & 7;
        *(uint4*)(Dz + (size_t)(bx * 64 + c) * 1024 + by * 64 + g * 8) = *(const uint4*)&T[c][g * 8];
    }
}

// single-matrix version for Wo
__global__ __launch_bounds__(256) void transp_cvt(
    const float* __restrict__ S, u16* __restrict__ D)
{
    __shared__ u16 T[64][72];
    const int tid = threadIdx.x;
    const int bx = blockIdx.x, by = blockIdx.y;
#pragma unroll
    for (int i = 0; i < 4; ++i) {
        int id = tid + i * 256;
        int fr = id >> 4, fc = id & 15;
        float4 v = *(const float4*)(S + (size_t)(by * 64 + fr) * 1024 + bx * 64 + fc * 4);
        T[fc * 4 + 0][fr] = f2bf(v.x);
        T[fc * 4 + 1][fr] = f2bf(v.y);
        T[fc * 4 + 2][fr] = f2bf(v.z);
        T[fc * 4 + 3][fr] = f2bf(v.w);
    }
    __syncthreads();
#pragma unroll
    for (int i = 0; i < 2; ++i) {
        int id = tid + i * 256;
        int c = id >> 3, g = id & 7;
        *(uint4*)(D + (size_t)(bx * 64 + c) * 1024 + by * 64 + g * 8) = *(const uint4*)&T[c][g * 8];
    }
}

// ---------------------------------------------------------------------------
// QKV = Xb @ [Wq|Wk|Wv]^T(k-major) + FUSED RoPE epilogue. Pure m97 structure.
// ---------------------------------------------------------------------------
__global__ __launch_bounds__(256) void gemm_qkv(
    const u16* __restrict__ A, const u16* __restrict__ Bt, u16* __restrict__ C)
{
    __shared__ u16 As[2][128][32];
    __shared__ u16 Bs[2][128][32];
    const int tid = threadIdx.x;
    const int lane = tid & 63, w = tid >> 6;
    const int col = lane & 15, quad = lane >> 4;
    const int bm = blockIdx.y << 7, bn = blockIdx.x << 7;
    const int wm = (w & 1) << 6, wn = (w >> 1) << 6;
    const int sr = lane >> 2, sc = (lane & 3) << 3;
    const f32x4 zero = {0.f, 0.f, 0.f, 0.f};
    f32x4 acc[4][4];
#pragma unroll
    for (int i = 0; i < 4; ++i)
#pragma unroll
        for (int j = 0; j < 4; ++j) acc[i][j] = zero;

#pragma unroll
    for (int i = 0; i < 2; ++i) {
        const int r0 = w * 32 + i * 16;
        cp16(A  + (size_t)(bm + r0 + sr) * 1024 + sc, &As[0][r0][0]);
        cp16(Bt + (size_t)(bn + r0 + sr) * 1024 + sc, &Bs[0][r0][0]);
    }

    for (int kc = 0; kc < 32; ++kc) {
        const int cur = kc & 1, nxt = cur ^ 1;
        __syncthreads();
        if (kc + 1 < 32) {
            const int k1 = (kc + 1) * 32;
#pragma unroll
            for (int i = 0; i < 2; ++i) {
                const int r0 = w * 32 + i * 16;
                cp16(A  + (size_t)(bm + r0 + sr) * 1024 + k1 + sc, &As[nxt][r0][0]);
                cp16(Bt + (size_t)(bn + r0 + sr) * 1024 + k1 + sc, &Bs[nxt][r0][0]);
            }
        }
        bf16x8 af[4], bfr[4];
#pragma unroll
        for (int i = 0; i < 4; ++i) af[i] = *(const bf16x8*)&As[cur][wm + i * 16 + col][quad * 8];
#pragma unroll
        for (int j = 0; j < 4; ++j) bfr[j] = *(const bf16x8*)&Bs[cur][wn + j * 16 + col][quad * 8];
#pragma unroll
        for (int i = 0; i < 4; ++i)
#pragma unroll
            for (int j = 0; j < 4; ++j)
                acc[i][j] = __builtin_amdgcn_mfma_f32_16x16x32_bf16(af[i], bfr[j], acc[i][j], 0, 0, 0);
    }

    // fused RoPE epilogue (Q and K blocks only)
    if (blockIdx.x < 16) {
        const float scale = (blockIdx.x < 8) ? 0.18033688011112042f : 1.0f;  // Q: (1/8)*log2e
        const float inv0 = __expf((float)col * -0.2878231366242557f);         // irope = col
        const float inv1 = __expf((float)(16 + col) * -0.2878231366242557f);  // irope = 16+col
#pragma unroll
        for (int i = 0; i < 4; ++i)
#pragma unroll
            for (int r = 0; r < 4; ++r) {
                const float t = (float)(bm + wm + i * 16 + quad * 4 + r);
                float s0, c0, s1, c1;
                __sincosf(t * inv0, &s0, &c0);
                __sincosf(t * inv1, &s1, &c1);
                float a0 = acc[i][0][r], b0 = acc[i][2][r];
                acc[i][0][r] = (a0 * c0 - b0 * s0) * scale;
                acc[i][2][r] = (b0 * c0 + a0 * s0) * scale;
                float a1 = acc[i][1][r], b1 = acc[i][3][r];
                acc[i][1][r] = (a1 * c1 - b1 * s1) * scale;
                acc[i][3][r] = (b1 * c1 + a1 * s1) * scale;
            }
    }
#pragma unroll
    for (int i = 0; i < 4; ++i)
#pragma unroll
        for (int j = 0; j < 4; ++j)
#pragma unroll
            for (int r = 0; r < 4; ++r)
                C[(size_t)(bm + wm + i * 16 + quad * 4 + r) * QKVS + bn + wn + j * 16 + col] =
                    f2bf(acc[i][j][r]);
}

// ---------------------------------------------------------------------------
// out = AO @ Wot^T. 128(M)x64(N) tiles, grid 16x32 = 512 blocks (2/CU).
// ---------------------------------------------------------------------------
__global__ __launch_bounds__(256) void gemm_out(
    const u16* __restrict__ A, const u16* __restrict__ Bt, float* __restrict__ C)
{
    __shared__ u16 As[2][128][32];
    __shared__ u16 Bs[2][64][32];
    const int tid = threadIdx.x;
    const int lane = tid & 63, w = tid >> 6;
    const int col = lane & 15, quad = lane >> 4;
    const int bm = blockIdx.y << 7, bn = blockIdx.x << 6;
    const int wm = (w & 1) << 6, wn = (w >> 1) << 5;
    const int sr = lane >> 2, sc = (lane & 3) << 3;
    const f32x4 zero = {0.f, 0.f, 0.f, 0.f};
    f32x4 acc[4][2];
#pragma unroll
    for (int i = 0; i < 4; ++i)
#pragma unroll
        for (int j = 0; j < 2; ++j) acc[i][j] = zero;

    {
#pragma unroll
        for (int i = 0; i < 2; ++i) {
            const int r0 = w * 32 + i * 16;
            cp16(A + (size_t)(bm + r0 + sr) * 1024 + sc, &As[0][r0][0]);
        }
        cp16(Bt + (size_t)(bn + w * 16 + sr) * 1024 + sc, &Bs[0][w * 16][0]);
    }

    for (int kc = 0; kc < 32; ++kc) {
        const int cur = kc & 1, nxt = cur ^ 1;
        __syncthreads();
        if (kc + 1 < 32) {
            const int k1 = (kc + 1) * 32;
#pragma unroll
            for (int i = 0; i < 2; ++i) {
                const int r0 = w * 32 + i * 16;
                cp16(A + (size_t)(bm + r0 + sr) * 1024 + k1 + sc, &As[nxt][r0][0]);
            }
            cp16(Bt + (size_t)(bn + w * 16 + sr) * 1024 + k1 + sc, &Bs[nxt][w * 16][0]);
        }
        bf16x8 af[4], bfr[2];
#pragma unroll
        for (int i = 0; i < 4; ++i) af[i] = *(const bf16x8*)&As[cur][wm + i * 16 + col][quad * 8];
#pragma unroll
        for (int j = 0; j < 2; ++j) bfr[j] = *(const bf16x8*)&Bs[cur][wn + j * 16 + col][quad * 8];
#pragma unroll
        for (int i = 0; i < 4; ++i)
#pragma unroll
            for (int j = 0; j < 2; ++j)
                acc[i][j] = __builtin_amdgcn_mfma_f32_16x16x32_bf16(af[i], bfr[j], acc[i][j], 0, 0, 0);
    }
#pragma unroll
    for (int i = 0; i < 4; ++i)
#pragma unroll
        for (int j = 0; j < 2; ++j)
#pragma unroll
            for (int r = 0; r < 4; ++r)
                C[(size_t)(bm + wm + i * 16 + quad * 4 + r) * 1024 + bn + wn + j * 16 + col] =
                    acc[i][j][r];
}

// ---------------------------------------------------------------------------
// Merge the two fp32 partials of each split diff job: AO = bf16((O0+O1)/(l0+l1)).
// Part layout in OS: pidx*8320 floats = O[128][64] row-major + l[128].
// Kernel boundary after attn gives cross-block coherence (no fences/atomics).
// ---------------------------------------------------------------------------
__global__ __launch_bounds__(256) void merge_attn(
    const float* __restrict__ OS, u16* __restrict__ AO)
{
    const int jid = blockIdx.x;            // 0..251
    const int h = 8 + (jid & 7), qt = jid >> 3;
    const float* P0 = OS + (size_t)(2 * jid) * 8320;
    const float* P1 = P0 + 8320;
    const int tid = threadIdx.x;
    const int q = tid >> 1, d0 = (tid & 1) * 32;
    const float inv = 1.f / (P0[8192 + q] + P1[8192 + q]);
    const float* a = P0 + q * 64 + d0;
    const float* b = P1 + q * 64 + d0;
    u16* dst = AO + (size_t)(qt * 128 + q) * 1024 + h * 64 + d0;
#pragma unroll
    for (int v = 0; v < 4; ++v) {
        u32 pk[4];
#pragma unroll
        for (int m = 0; m < 4; ++m) {
            const int e = v * 8 + m * 2;
            float lo = (a[e] + b[e]) * inv;
            float hi = (a[e + 1] + b[e + 1]) * inv;
            pk[m] = ((u32)f2bf(lo)) | (((u32)f2bf(hi)) << 16);
        }
        uint4 o; o.x = pk[0]; o.y = pk[1]; o.z = pk[2]; o.w = pk[3];
        *(uint4*)(dst + v * 8) = o;
    }
}

// ---------------------------------------------------------------------------
// MFMA flash attention v11 — r5/r7 pipeline + merge-free-in-kernel KV split:
//  * 252 of 256 diff jobs split into two 16-chunk halves (504 parts); parts
//    write fp32 (O,l) partials to d_out scratch with PLAIN stores; a separate
//    merge kernel combines them (kernel boundary = coherence; r4/r6 lessons:
//    no atomics, no fences, no same-kernel cross-block reads).
//  * Grid 768 (4 dummy exits). bid mapping designed so round-robin triples
//    (b, b+256, b+512) sum to 48-49 chunk-units:
//      t<128:   slot0 causal(qt=t>>3), slot1 causal(31-qt), slot2 part  = 49
//      t<252:   3 parts                                                 = 48
//      t<256:   slot0 unsplit diff(32), slot1 part, slot2 dummy         = 48
//    Robust to mapping being wrong: 768 fine blocks at 3/CU LDS residency
//    (3x50176 = 150.5KB <= 160KB) bound the worst CU regardless.
//  * Per-chunk pipeline unchanged (cperm Vt single-buf, K=32 PV, ks-outer S,
//    setprio, 2 barriers/chunk).
// ---------------------------------------------------------------------------
__global__ __launch_bounds__(256) void attn_mfma(
    const u16* __restrict__ QKV, u16* __restrict__ AO, float* __restrict__ OS)
{
    __shared__ u16 Ks[2][128][64];   // [key][dim], unpadded, XOR-swizzled 16B blocks
    __shared__ u16 Vt[64][136];      // [dim][cperm(key)] single-buffered + 8-u16 pad
    const int bid = blockIdx.x;
    const int t = bid & 255, slot = bid >> 8;
    int h, qt, c0, c1;
    int pidx = -1;
    if (t < 128) {
        if (slot == 0)      { h = t & 7; qt = t >> 3; }
        else if (slot == 1) { h = t & 7; qt = 31 - (t >> 3); }
        else                { pidx = t; }
    } else if (t < 252) {
        pidx = 128 + 3 * (t - 128) + slot;
    } else {
        if (slot == 0)      { h = 8 + (t & 7); qt = t >> 3; }       // qt=31, h=12..15
        else if (slot == 1) { pidx = 500 + (t - 252); }
        else return;                                                 // dummy
    }
    bool split = false;
    if (pidx >= 0) {
        split = true;
        const int jid = pidx >> 1, p = pidx & 1;
        h = 8 + (jid & 7); qt = jid >> 3;
        c0 = p * 16; c1 = c0 + 16;
    } else {
        c0 = 0; c1 = (h < NAR) ? (qt + 1) : 32;
    }
    const bool causal = (h < NAR);
    const int tid = threadIdx.x;
    const int w = tid >> 6, lane = tid & 63;
    const int col = lane & 15, quad = lane >> 4;
    const int qb = qt * 128;
    const int qr0 = qb + w * 32 + col;
    const int qr1 = qr0 + 16;
    // column-permuted position of key a=2*lane (a's pair b=a+1 sits at cva+1)
    const int cva = ((lane >> 1) & 3) * 32 + (lane >> 3) * 4 + (lane & 1) * 2;

    // hoisted Q B-frags (rope'd, pre-scaled by 0.125*log2e in gemm_qkv)
    bf16x8 qf[2][2];
#pragma unroll
    for (int s = 0; s < 2; ++s)
#pragma unroll
        for (int ks = 0; ks < 2; ++ks)
            qf[s][ks] = *(const bf16x8*)(QKV + (size_t)(qr0 + s * 16) * QKVS +
                                         h * DHEAD + ks * 32 + quad * 8);

    bf16x8 ones8;
#pragma unroll
    for (int i = 0; i < 8; ++i) ones8[i] = (short)0x3F80;

    const f32x4 zero = {0.f, 0.f, 0.f, 0.f};
    f32x4 O[2][5];  // [set][nd] O^T tiles (d = nd*16+quad*4+r, q = col); nd=4 = l
#pragma unroll
    for (int s = 0; s < 2; ++s)
#pragma unroll
        for (int nd = 0; nd < 5; ++nd) O[s][nd] = zero;

    const int krow = lane >> 3;
    const int kcb = (lane & 7) ^ krow;
    const u16* kbase = QKV + (size_t)krow * QKVS + 1024 + h * DHEAD + kcb * 8;
    const u16* vbase = QKV + (size_t)(lane * 2) * QKVS + 2048 + h * DHEAD + w * 16;

    u32x4 vA0, vA1, vB0, vB1;   // pending V(ch) regs for end-of-iter Vt write
    bf16x8 pf8[2][4];           // P(ch) frags: pf8[s][tp] = keys 32tp..32tp+31 (permuted)

#define VT_WRITE()                                                                                 \
    _Pragma("unroll")                                                                              \
    for (int j = 0; j < 4; ++j) {                                                                  \
        *(u32*)&Vt[w * 16 + 2 * j][cva]         = __builtin_amdgcn_perm(vB0[j], vA0[j], 0x05040100u); \
        *(u32*)&Vt[w * 16 + 2 * j + 1][cva]     = __builtin_amdgcn_perm(vB0[j], vA0[j], 0x07060302u); \
        *(u32*)&Vt[w * 16 + 8 + 2 * j][cva]     = __builtin_amdgcn_perm(vB1[j], vA1[j], 0x05040100u); \
        *(u32*)&Vt[w * 16 + 8 + 2 * j + 1][cva] = __builtin_amdgcn_perm(vB1[j], vA1[j], 0x07060302u); \
    }

// PV burst over Vt at K=32: tp-outer, l-row folded in -> acc reuse distance 10.
#define PV_STEP()                                                                                  \
    {                                                                                              \
        __builtin_amdgcn_s_setprio(1);                                                             \
        _Pragma("unroll")                                                                          \
        for (int tp = 0; tp < 4; ++tp) {                                                           \
            bf16x8 vv[4];                                                                          \
            _Pragma("unroll")                                                                      \
            for (int nd = 0; nd < 4; ++nd)                                                         \
                vv[nd] = *(const bf16x8*)&Vt[nd * 16 + col][quad * 32 + tp * 8];                   \
            _Pragma("unroll")                                                                      \
            for (int nd = 0; nd < 4; ++nd) {                                                       \
                O[0][nd] = __builtin_amdgcn_mfma_f32_16x16x32_bf16(vv[nd], pf8[0][tp], O[0][nd], 0, 0, 0); \
                O[1][nd] = __builtin_amdgcn_mfma_f32_16x16x32_bf16(vv[nd], pf8[1][tp], O[1][nd], 0, 0, 0); \
            }                                                                                      \
            O[0][4] = __builtin_amdgcn_mfma_f32_16x16x32_bf16(ones8, pf8[0][tp], O[0][4], 0, 0, 0); \
            O[1][4] = __builtin_amdgcn_mfma_f32_16x16x32_bf16(ones8, pf8[1][tp], O[1][4], 0, 0, 0); \
        }                                                                                          \
        __builtin_amdgcn_s_setprio(0);                                                             \
    }

// S(CH) + exp -> pf8. ks-outer: st[s][jj] reuse distance 8.
#define S_STEP(KBUF, CH)                                                                           \
    {                                                                                              \
        const bool mask = causal && ((CH) == qt);                                                  \
        _Pragma("unroll")                                                                          \
        for (int hf = 0; hf < 2; ++hf) {                                                           \
            f32x4 st[2][4];                                                                        \
            _Pragma("unroll")                                                                      \
            for (int s = 0; s < 2; ++s)                                                            \
                _Pragma("unroll")                                                                  \
                for (int jj = 0; jj < 4; ++jj) st[s][jj] = zero;                                   \
            __builtin_amdgcn_s_setprio(1);                                                         \
            _Pragma("unroll")                                                                      \
            for (int ks = 0; ks < 2; ++ks)                                                         \
                _Pragma("unroll")                                                                  \
                for (int jj = 0; jj < 4; ++jj) {                                                   \
                    bf16x8 kf = *(const bf16x8*)&Ks[KBUF][(hf * 4 + jj) * 16 + col]                \
                                                         [((ks * 4 + quad) ^ (col & 7)) * 8];      \
                    st[0][jj] = __builtin_amdgcn_mfma_f32_16x16x32_bf16(kf, qf[0][ks], st[0][jj], 0, 0, 0); \
                    st[1][jj] = __builtin_amdgcn_mfma_f32_16x16x32_bf16(kf, qf[1][ks], st[1][jj], 0, 0, 0); \
                }                                                                                  \
            __builtin_amdgcn_s_setprio(0);                                                         \
            if (mask) {                                                                            \
                _Pragma("unroll")                                                                  \
                for (int jj = 0; jj < 4; ++jj) {                                                   \
                    const int kk = (CH) * 128 + (hf * 4 + jj) * 16 + quad * 4;                     \
                    _Pragma("unroll")                                                              \
                    for (int r = 0; r < 4; ++r) {                                                  \
                        if (kk + r > qr0) st[0][jj][r] = -1e30f;                                   \
                        if (kk + r > qr1) st[1][jj][r] = -1e30f;                                   \
                    }                                                                              \
                }                                                                                  \
            }                                                                                      \
            _Pragma("unroll")                                                                      \
            for (int s = 0; s < 2; ++s)                                                            \
                _Pragma("unroll")                                                                  \
                for (int jj = 0; jj < 4; ++jj) {                                                   \
                    u32 plo = packtr(__builtin_amdgcn_exp2f(st[s][jj][0]),                         \
                                     __builtin_amdgcn_exp2f(st[s][jj][1]));                        \
                    u32 phi = packtr(__builtin_amdgcn_exp2f(st[s][jj][2]),                         \
                                     __builtin_amdgcn_exp2f(st[s][jj][3]));                        \
                    u32* p = (u32*)&pf8[s][0] + (hf * 4 + jj) * 2;                                 \
                    p[0] = plo; p[1] = phi;                                                        \
                }                                                                                  \
        }                                                                                          \
    }

    // ---- prologue: stage chunk c0 into Ks[0] ----
#pragma unroll
    for (int i = 0; i < 4; ++i)
        cp16(kbase + (size_t)(c0 * 128 + (i * 4 + w) * 8) * QKVS, &Ks[0][(i * 4 + w) * 8][0]);
    {
        const u16* vp = vbase + (size_t)c0 * 128 * QKVS;
        vA0 = *(u32x4*)(vp);
        vA1 = *(u32x4*)(vp + 8);
        vB0 = *(u32x4*)(vp + QKVS);
        vB1 = *(u32x4*)(vp + QKVS + 8);
    }
    __syncthreads();  // K(c0) in LDS, V(c0) in regs
    VT_WRITE();       // Vt <- V(c0)
    if (c1 - c0 > 1) {  // prefetch K(c0+1)
#pragma unroll
        for (int i = 0; i < 4; ++i)
            cp16(kbase + (size_t)((c0 + 1) * 128 + (i * 4 + w) * 8) * QKVS, &Ks[1][(i * 4 + w) * 8][0]);
    }
    S_STEP(0, c0);    // pf8 = P(c0)

    // ---- main loop ----
    for (int ch = c0 + 1; ch < c1; ++ch) {
        const int rel = (ch - c0) & 1;
        __syncthreads();  // barrier_a: Ks[rel]=K(ch) drained; Vt=V(ch-1) visible
        if (ch + 1 < c1) {  // prefetch K(ch+1) into buffer S(ch) is NOT reading
            const size_t cc = (size_t)(ch + 1) * 128;
#pragma unroll
            for (int i = 0; i < 4; ++i)
                cp16(kbase + (cc + (i * 4 + w) * 8) * QKVS, &Ks[rel ^ 1][(i * 4 + w) * 8][0]);
        }
        {   // V(ch) regs for end-of-iter Vt write
            const u16* vp = vbase + (size_t)ch * 128 * QKVS;
            vA0 = *(u32x4*)(vp);
            vA1 = *(u32x4*)(vp + 8);
            vB0 = *(u32x4*)(vp + QKVS);
            vB1 = *(u32x4*)(vp + QKVS + 8);
        }
        PV_STEP();        // P(ch-1) x V(ch-1)
        S_STEP(rel, ch);  // -> pf8 = P(ch)
        __syncthreads();  // barrier_b: all PV reads done; loads above drained
        VT_WRITE();       // Vt <- V(ch)
    }

    // ---- tail: PV(c1-1) ----
    __syncthreads();
    PV_STEP();

    if (!split) {
        // direct epilogue: l in-lane (col=q); O^T rows d = nd*16+quad*4+r
#pragma unroll
        for (int s = 0; s < 2; ++s) {
            const float inv = 1.f / O[s][4][0];
            const int qrow = qr0 + s * 16;
#pragma unroll
            for (int nd = 0; nd < 4; ++nd) {
                ushort4 ov;
                ov.x = f2bf(O[s][nd][0] * inv);
                ov.y = f2bf(O[s][nd][1] * inv);
                ov.z = f2bf(O[s][nd][2] * inv);
                ov.w = f2bf(O[s][nd][3] * inv);
                *(ushort4*)(AO + (size_t)qrow * 1024 + h * DHEAD + nd * 16 + quad * 4) = ov;
            }
        }
    } else {
        // partial epilogue: plain fp32 stores; merge kernel combines later
        float* P = OS + (size_t)pidx * 8320;
        const int ql = w * 32 + col;
#pragma unroll
        for (int s = 0; s < 2; ++s) {
            const int q = ql + s * 16;
#pragma unroll
            for (int nd = 0; nd < 4; ++nd)
                *(f32x4*)(P + q * 64 + nd * 16 + quad * 4) = O[s][nd];
            if (quad == 0) P[8192 + q] = O[s][4][0];
        }
    }
#undef VT_WRITE
#undef PV_STEP
#undef S_STEP
}

// ---------------------------------------------------------------------------
extern "C" void kernel_launch(void* const* d_in, const int* in_sizes, int n_in,
                              void* d_out, int out_size, void* d_ws, size_t ws_size,
                              hipStream_t stream)
{
    const float* X  = (const float*)d_in[0];
    const float* Wq = (const float*)d_in[1];
    const float* Wk = (const float*)d_in[2];
    const float* Wv = (const float*)d_in[3];
    const float* Wo = (const float*)d_in[4];
    float* out = (float*)d_out;

    // ws (u16 units), liveness overlays:
    //   [0 .. 4M):   Wqkvt [3072][1024] (dead after gemm_qkv) -> AOb [4096][1024]
    //   [4M .. 16M): QKV [4096][3072] (dead after attn) -> Wot [1024][1024]
    // d_out (16.78 MB) timeline: Xb (bf16 X, 8 MB) for gemm_qkv -> OS partials
    //   504 x 8320 fp32 (16.77 MB) written by attn, read by merge_attn ->
    //   final out written by gemm_out.
    u16* Wt  = (u16*)d_ws;
    u16* AOb = (u16*)d_ws;
    u16* QKV = (u16*)d_ws + (size_t)4 * 1024 * 1024;
    u16* Wot = QKV;
    u16* Xb  = (u16*)out;
    float* OS = out;

    xcast<<<2048, 256, 0, stream>>>(X, Xb);
    transp_cvt3<<<dim3(16, 16, 3), 256, 0, stream>>>(Wq, Wk, Wv, Wt);
    gemm_qkv<<<dim3(24, 32), 256, 0, stream>>>(Xb, Wt, QKV);  // rope fused in epilogue
    attn_mfma<<<768, 256, 0, stream>>>(QKV, AOb, OS);         // Xb dead now
    transp_cvt<<<dim3(16, 16), 256, 0, stream>>>(Wo, Wot);    // QKV dead after attn
    merge_attn<<<252, 256, 0, stream>>>(OS, AOb);
    gemm_out<<<dim3(16, 32), 256, 0, stream>>>(AOb, Wot, out); // overwrites OS
}